// Round 1
// baseline (953.342 us; speedup 1.0000x reference)
//
#include <hip/hip_runtime.h>

#define N_NODES 100000
#define N_EDGES 1600000
#define D 128

// ---------------- degree / CSR build ----------------

__global__ void k_zero_deg(int* __restrict__ deg) {
    int i = blockIdx.x * blockDim.x + threadIdx.x;
    if (i < N_NODES) deg[i] = 0;
}

__global__ void k_count_deg(const int* __restrict__ dst, int* __restrict__ deg) {
    int e = blockIdx.x * blockDim.x + threadIdx.x;
    if (e < N_EDGES) atomicAdd(&deg[dst[e]], 1);
}

// exclusive scan, stage 1: per-1024 block scan
__global__ void k_scan1(const int* __restrict__ deg, int* __restrict__ ex,
                        int* __restrict__ bsum) {
    __shared__ int s[1024];
    int t = threadIdx.x;
    int i = blockIdx.x * 1024 + t;
    int v = (i < N_NODES) ? deg[i] : 0;
    s[t] = v;
    __syncthreads();
    for (int o = 1; o < 1024; o <<= 1) {
        int x = (t >= o) ? s[t - o] : 0;
        __syncthreads();
        s[t] += x;
        __syncthreads();
    }
    if (i < N_NODES) ex[i] = s[t] - v;          // exclusive within block
    if (t == 1023) bsum[blockIdx.x] = s[t];     // block total
}

// stage 2: scan the (<=128) block sums, single block
__global__ void k_scan2(int* __restrict__ bsum, int nb) {
    __shared__ int s[128];
    int t = threadIdx.x;
    int v = (t < nb) ? bsum[t] : 0;
    s[t] = v;
    __syncthreads();
    for (int o = 1; o < 128; o <<= 1) {
        int x = (t >= o) ? s[t - o] : 0;
        __syncthreads();
        s[t] += x;
        __syncthreads();
    }
    if (t < nb) bsum[t] = s[t] - v;             // exclusive block offsets
}

// stage 3: finalize row_start, init cursor, inv_deg
__global__ void k_scan3(const int* __restrict__ deg, int* __restrict__ ex,
                        const int* __restrict__ bsum, int* __restrict__ cursor,
                        float* __restrict__ inv_deg) {
    int i = blockIdx.x * blockDim.x + threadIdx.x;
    if (i >= N_NODES) return;
    int rs = ex[i] + bsum[i >> 10];
    ex[i] = rs;
    cursor[i] = rs;
    int d = deg[i];
    inv_deg[i] = 1.0f / (float)max(d, 1);
}

__global__ void k_sort(const int* __restrict__ src, const int* __restrict__ dst,
                       int* __restrict__ cursor, int* __restrict__ sorted_src) {
    int e = blockIdx.x * blockDim.x + threadIdx.x;
    if (e < N_EDGES) {
        int p = atomicAdd(&cursor[dst[e]], 1);
        sorted_src[p] = src[e];
    }
}

// ---------------- weight transpose (one-off, tiny) ----------------
// Wt[k][o] = W[o][k]   (128x128)
__global__ void k_transpose(const float* __restrict__ W, float* __restrict__ Wt) {
    int idx = blockIdx.x * 256 + threadIdx.x;   // 64 blocks x 256 = 16384
    int o = idx >> 7, k = idx & 127;
    Wt[k * 128 + o] = W[idx];
}

// ---------------- f32 GEMM: out[N][128] = A[N][128] @ Wt (+bias) ----------------
// Block: 256 threads, 64-row tile. LDS: A-tile 32KB + 64-k weight chunk 32KB = 64KB.
// Per thread: 8 rows x 4 cols register tile -> VALU-bound.
template <bool BIAS>
__global__ __launch_bounds__(256) void k_gemm(const float* __restrict__ A,
                                              const float* __restrict__ Wt,
                                              const float* __restrict__ bias,
                                              float* __restrict__ out) {
    __shared__ float a_s[64][128];
    __shared__ float w_s[64][128];
    const int t = threadIdx.x;
    const int row0 = blockIdx.x * 64;

    // stage A tile (guard OOB rows with zeros)
#pragma unroll
    for (int p = 0; p < 8; ++p) {
        int idx = t + p * 256;          // float4 index, 0..2047
        int r = idx >> 5, c4 = idx & 31;
        float4 v = make_float4(0.f, 0.f, 0.f, 0.f);
        if (row0 + r < N_NODES)
            v = *(const float4*)&A[(size_t)(row0 + r) * 128 + c4 * 4];
        *(float4*)&a_s[r][c4 * 4] = v;
    }

    const int r0 = (t >> 5) * 8;        // 8 row-groups of 8
    const int c0 = (t & 31) * 4;        // 32 col-groups of 4
    float4 acc[8];
#pragma unroll
    for (int r = 0; r < 8; ++r) acc[r] = make_float4(0.f, 0.f, 0.f, 0.f);

    for (int ch = 0; ch < 2; ++ch) {    // two 64-wide k chunks
        __syncthreads();                // prev compute done before overwriting w_s
#pragma unroll
        for (int p = 0; p < 8; ++p) {
            int idx = t + p * 256;
            int kk = idx >> 5, o4 = idx & 31;
            *(float4*)&w_s[kk][o4 * 4] =
                *(const float4*)&Wt[(size_t)(ch * 64 + kk) * 128 + o4 * 4];
        }
        __syncthreads();
#pragma unroll
        for (int kk = 0; kk < 64; kk += 4) {
            float4 w0 = *(float4*)&w_s[kk + 0][c0];
            float4 w1 = *(float4*)&w_s[kk + 1][c0];
            float4 w2 = *(float4*)&w_s[kk + 2][c0];
            float4 w3 = *(float4*)&w_s[kk + 3][c0];
#pragma unroll
            for (int r = 0; r < 8; ++r) {
                float4 a = *(float4*)&a_s[r0 + r][ch * 64 + kk];
                acc[r].x += a.x * w0.x + a.y * w1.x + a.z * w2.x + a.w * w3.x;
                acc[r].y += a.x * w0.y + a.y * w1.y + a.z * w2.y + a.w * w3.y;
                acc[r].z += a.x * w0.z + a.y * w1.z + a.z * w2.z + a.w * w3.z;
                acc[r].w += a.x * w0.w + a.y * w1.w + a.z * w2.w + a.w * w3.w;
            }
        }
    }

    float4 b = make_float4(0.f, 0.f, 0.f, 0.f);
    if (BIAS) b = *(const float4*)&bias[c0];
#pragma unroll
    for (int r = 0; r < 8; ++r) {
        int row = row0 + r0 + r;
        if (row < N_NODES) {
            float4 v;
            v.x = acc[r].x + b.x; v.y = acc[r].y + b.y;
            v.z = acc[r].z + b.z; v.w = acc[r].w + b.w;
            *(float4*)&out[(size_t)row * 128 + c0] = v;
        }
    }
}

// ---------------- pull aggregation: io[i] (+)= inv_deg[i] * sum_j t[nbr_j], opt relu ----
// one 64-lane wave per node; lane covers 2 dims (float2)
template <bool RELU>
__global__ void k_agg(const float* __restrict__ t_mat, const int* __restrict__ sorted_src,
                      const int* __restrict__ row_start, const int* __restrict__ deg,
                      const float* __restrict__ inv_deg, float* __restrict__ io) {
    int w = (blockIdx.x * blockDim.x + threadIdx.x) >> 6;
    int lane = threadIdx.x & 63;
    if (w >= N_NODES) return;
    int rs = row_start[w];
    int d = deg[w];
    float accx = 0.f, accy = 0.f;
    for (int q0 = 0; q0 < d; q0 += 64) {
        int nb = 0;
        if (q0 + lane < d) nb = sorted_src[rs + q0 + lane];
        int m = min(64, d - q0);
        for (int q = 0; q < m; ++q) {
            int j = __shfl(nb, q);
            float2 v = *(const float2*)&t_mat[(size_t)j * 128 + lane * 2];
            accx += v.x;
            accy += v.y;
        }
    }
    float inv = inv_deg[w];
    size_t o = (size_t)w * 128 + lane * 2;
    float2 cur = *(const float2*)&io[o];
    float rx = cur.x + inv * accx;
    float ry = cur.y + inv * accy;
    if (RELU) { rx = fmaxf(rx, 0.f); ry = fmaxf(ry, 0.f); }
    float2 res; res.x = rx; res.y = ry;
    *(float2*)&io[o] = res;
}

// ---------------- launch ----------------

extern "C" void kernel_launch(void* const* d_in, const int* in_sizes, int n_in,
                              void* d_out, int out_size, void* d_ws, size_t ws_size,
                              hipStream_t stream) {
    const float* x   = (const float*)d_in[0];
    const int*   ei  = (const int*)d_in[1];      // [2][E] int32
    const float* W1l = (const float*)d_in[2];
    const float* W1r = (const float*)d_in[3];
    const float* b1  = (const float*)d_in[4];
    const float* W2l = (const float*)d_in[5];
    const float* W2r = (const float*)d_in[6];
    const float* b2  = (const float*)d_in[7];
    float* out = (float*)d_out;

    const int* src = ei;
    const int* dst = ei + N_EDGES;

    // workspace carve-up (256B aligned)
    char* p = (char*)d_ws;
    auto alloc = [&](size_t bytes) {
        char* r = p;
        p += (bytes + 255) & ~(size_t)255;
        return r;
    };
    float* t_buf   = (float*)alloc((size_t)N_NODES * D * sizeof(float)); // 51.2MB
    float* h_buf   = (float*)alloc((size_t)N_NODES * D * sizeof(float)); // 51.2MB
    int*   deg     = (int*)  alloc((size_t)N_NODES * sizeof(int));
    int*   rstart  = (int*)  alloc((size_t)N_NODES * sizeof(int));
    int*   cursor  = (int*)  alloc((size_t)N_NODES * sizeof(int));
    float* inv_deg = (float*)alloc((size_t)N_NODES * sizeof(float));
    int*   ssrc    = (int*)  alloc((size_t)N_EDGES * sizeof(int));
    int*   bsum    = (int*)  alloc(128 * sizeof(int));
    float* wt1l    = (float*)alloc(128 * 128 * sizeof(float));
    float* wt1r    = (float*)alloc(128 * 128 * sizeof(float));
    float* wt2l    = (float*)alloc(128 * 128 * sizeof(float));
    float* wt2r    = (float*)alloc(128 * 128 * sizeof(float));

    const int nb1024 = (N_NODES + 1023) / 1024;  // 98

    // CSR build
    k_zero_deg<<<(N_NODES + 255) / 256, 256, 0, stream>>>(deg);
    k_count_deg<<<(N_EDGES + 255) / 256, 256, 0, stream>>>(dst, deg);
    k_scan1<<<nb1024, 1024, 0, stream>>>(deg, rstart, bsum);
    k_scan2<<<1, 128, 0, stream>>>(bsum, nb1024);
    k_scan3<<<(N_NODES + 255) / 256, 256, 0, stream>>>(deg, rstart, bsum, cursor, inv_deg);
    k_sort<<<(N_EDGES + 255) / 256, 256, 0, stream>>>(src, dst, cursor, ssrc);

    // weight transposes
    k_transpose<<<64, 256, 0, stream>>>(W1l, wt1l);
    k_transpose<<<64, 256, 0, stream>>>(W1r, wt1r);
    k_transpose<<<64, 256, 0, stream>>>(W2l, wt2l);
    k_transpose<<<64, 256, 0, stream>>>(W2r, wt2r);

    const int gemm_grid = (N_NODES + 63) / 64;   // 1563
    const int agg_grid  = N_NODES / 4;           // 4 waves/block

    // layer 1: t = x @ W1l.T ; h = x @ W1r.T + b1 ; h = relu(h + inv*sum t[nbrs])
    k_gemm<false><<<gemm_grid, 256, 0, stream>>>(x, wt1l, nullptr, t_buf);
    k_gemm<true ><<<gemm_grid, 256, 0, stream>>>(x, wt1r, b1, h_buf);
    k_agg<true><<<agg_grid, 256, 0, stream>>>(t_buf, ssrc, rstart, deg, inv_deg, h_buf);

    // layer 2: t = h @ W2l.T ; out = h @ W2r.T + b2 ; out += inv*sum t[nbrs]
    k_gemm<false><<<gemm_grid, 256, 0, stream>>>(h_buf, wt2l, nullptr, t_buf);
    k_gemm<true ><<<gemm_grid, 256, 0, stream>>>(h_buf, wt2r, b2, out);
    k_agg<false><<<agg_grid, 256, 0, stream>>>(t_buf, ssrc, rstart, deg, inv_deg, out);
}

// Round 2
// 498.236 us; speedup vs baseline: 1.9134x; 1.9134x over previous
//
#include <hip/hip_runtime.h>

#define N_NODES 100000
#define N_EDGES 1600000
#define D 128

typedef __attribute__((ext_vector_type(8))) short short8v;
typedef __attribute__((ext_vector_type(4))) float f32x4;

__device__ __forceinline__ unsigned short f2bf(float f) {
    unsigned int u = __float_as_uint(f);
    unsigned int r = (u + 0x7fffu + ((u >> 16) & 1u)) >> 16;
    return (unsigned short)r;
}
__device__ __forceinline__ float bf2f(unsigned int lo16) {
    return __uint_as_float(lo16 << 16);
}
__device__ __forceinline__ short8v zero8() {
    short8v z = {0, 0, 0, 0, 0, 0, 0, 0};
    return z;
}

// ---------------- degree / CSR build ----------------

__global__ void k_zero_deg(int* __restrict__ deg) {
    int i = blockIdx.x * blockDim.x + threadIdx.x;
    if (i < N_NODES) deg[i] = 0;
}

__global__ void k_count_deg(const int* __restrict__ dst, int* __restrict__ deg) {
    int e = blockIdx.x * blockDim.x + threadIdx.x;
    if (e < N_EDGES) atomicAdd(&deg[dst[e]], 1);
}

__global__ void k_scan1(const int* __restrict__ deg, int* __restrict__ ex,
                        int* __restrict__ bsum) {
    __shared__ int s[1024];
    int t = threadIdx.x;
    int i = blockIdx.x * 1024 + t;
    int v = (i < N_NODES) ? deg[i] : 0;
    s[t] = v;
    __syncthreads();
    for (int o = 1; o < 1024; o <<= 1) {
        int x = (t >= o) ? s[t - o] : 0;
        __syncthreads();
        s[t] += x;
        __syncthreads();
    }
    if (i < N_NODES) ex[i] = s[t] - v;
    if (t == 1023) bsum[blockIdx.x] = s[t];
}

__global__ void k_scan2(int* __restrict__ bsum, int nb) {
    __shared__ int s[128];
    int t = threadIdx.x;
    int v = (t < nb) ? bsum[t] : 0;
    s[t] = v;
    __syncthreads();
    for (int o = 1; o < 128; o <<= 1) {
        int x = (t >= o) ? s[t - o] : 0;
        __syncthreads();
        s[t] += x;
        __syncthreads();
    }
    if (t < nb) bsum[t] = s[t] - v;
}

__global__ void k_scan3(const int* __restrict__ deg, int* __restrict__ ex,
                        const int* __restrict__ bsum, int* __restrict__ cursor,
                        float* __restrict__ inv_deg) {
    int i = blockIdx.x * blockDim.x + threadIdx.x;
    if (i >= N_NODES) return;
    int rs = ex[i] + bsum[i >> 10];
    ex[i] = rs;
    cursor[i] = rs;
    inv_deg[i] = 1.0f / (float)max(deg[i], 1);
}

__global__ void k_sort(const int* __restrict__ src, const int* __restrict__ dst,
                       int* __restrict__ cursor, int* __restrict__ sorted_src) {
    int e = blockIdx.x * blockDim.x + threadIdx.x;
    if (e < N_EDGES) {
        int p = atomicAdd(&cursor[dst[e]], 1);
        sorted_src[p] = src[e];
    }
}

// ---------------- casts / weight packing ----------------

__global__ void k_cast_bf16(const float* __restrict__ in, unsigned short* __restrict__ out) {
    int i = blockIdx.x * blockDim.x + threadIdx.x;      // 4 elems each
    float4 v = *(const float4*)&in[(size_t)i * 4];
    uint2 o;
    o.x = (unsigned int)f2bf(v.x) | ((unsigned int)f2bf(v.y) << 16);
    o.y = (unsigned int)f2bf(v.z) | ((unsigned int)f2bf(v.w) << 16);
    *(uint2*)&out[(size_t)i * 4] = o;
}

// Wcat[n][k] bf16, n in [0,256): rows 0..127 = Wl, 128..255 = Wr  (both [o][k] row-major)
__global__ void k_pack_w(const float* __restrict__ Wl, const float* __restrict__ Wr,
                         unsigned short* __restrict__ Wcat) {
    int idx = blockIdx.x * blockDim.x + threadIdx.x;    // 0..32767
    float v = (idx < 16384) ? Wl[idx] : Wr[idx - 16384];
    Wcat[idx] = f2bf(v);
}

// ---------------- fused bf16 MFMA GEMM: [N x 128] @ [128 x 256] ----------------
// cols 0..127 -> Tout (bf16, feeds aggregation); cols 128..255 -> Hout (+bias)
// block = 256 thr = 4 waves; wave w owns cols 64w..64w+63; 64-row tiles, grid-stride.
// No LDS: B frags in registers (64 VGPR), A frags straight from global (64B segments).
template <bool OUT_F32>
__global__ __launch_bounds__(256) void k_gemm_mfma(
    const unsigned short* __restrict__ A,    // [N][128] bf16
    const unsigned short* __restrict__ Bt,   // [256][128] bf16
    const float* __restrict__ bias,          // [128]
    unsigned short* __restrict__ Tout,       // [N][128] bf16
    void* __restrict__ Hout)                 // [N][128] bf16 or f32
{
    const int wid = threadIdx.x >> 6;
    const int lane = threadIdx.x & 63;
    const int l15 = lane & 15, lg = lane >> 4;
    const int col_base = wid * 64;

    // B fragments for this wave's 64 cols (Bt row-major == B-operand layout)
    short8v bfrag[4][4];                     // [cg][ks]
#pragma unroll
    for (int cg = 0; cg < 4; ++cg)
#pragma unroll
        for (int ks = 0; ks < 4; ++ks)
            bfrag[cg][ks] = *(const short8v*)&Bt[(size_t)(col_base + cg * 16 + l15) * 128
                                                 + ks * 32 + lg * 8];
    // bias per col-group (only h waves use it)
    float bv[4];
#pragma unroll
    for (int cg = 0; cg < 4; ++cg)
        bv[cg] = (wid >= 2) ? bias[(wid - 2) * 64 + cg * 16 + l15] : 0.0f;

    const int ntiles = (N_NODES + 63) / 64;
    for (int tile = blockIdx.x; tile < ntiles; tile += gridDim.x) {
        const int row0 = tile * 64;
        f32x4 acc[4][4];                     // [rg][cg]
#pragma unroll
        for (int rg = 0; rg < 4; ++rg)
#pragma unroll
            for (int cg = 0; cg < 4; ++cg)
                acc[rg][cg] = (f32x4){0.f, 0.f, 0.f, 0.f};

#pragma unroll
        for (int rg = 0; rg < 4; ++rg) {
            const int arow = row0 + rg * 16 + l15;
            short8v afrag[4];
            if (arow < N_NODES) {
#pragma unroll
                for (int ks = 0; ks < 4; ++ks)
                    afrag[ks] = *(const short8v*)&A[(size_t)arow * 128 + ks * 32 + lg * 8];
            } else {
#pragma unroll
                for (int ks = 0; ks < 4; ++ks) afrag[ks] = zero8();
            }
#pragma unroll
            for (int cg = 0; cg < 4; ++cg)
#pragma unroll
                for (int ks = 0; ks < 4; ++ks)
                    acc[rg][cg] = __builtin_amdgcn_mfma_f32_16x16x32_bf16(
                        afrag[ks], bfrag[cg][ks], acc[rg][cg], 0, 0, 0);
        }

        // write out: row = row0 + rg*16 + lg*4 + i, col = col_base + cg*16 + l15
        if (wid < 2) {
#pragma unroll
            for (int rg = 0; rg < 4; ++rg) {
                const int rbase = row0 + rg * 16 + lg * 4;
#pragma unroll
                for (int cg = 0; cg < 4; ++cg) {
                    const int col = col_base + cg * 16 + l15;
#pragma unroll
                    for (int i = 0; i < 4; ++i) {
                        int row = rbase + i;
                        if (row < N_NODES)
                            Tout[(size_t)row * 128 + col] = f2bf(acc[rg][cg][i]);
                    }
                }
            }
        } else {
#pragma unroll
            for (int rg = 0; rg < 4; ++rg) {
                const int rbase = row0 + rg * 16 + lg * 4;
#pragma unroll
                for (int cg = 0; cg < 4; ++cg) {
                    const int col = (wid - 2) * 64 + cg * 16 + l15;
#pragma unroll
                    for (int i = 0; i < 4; ++i) {
                        int row = rbase + i;
                        if (row < N_NODES) {
                            float v = acc[rg][cg][i] + bv[cg];
                            if (OUT_F32)
                                ((float*)Hout)[(size_t)row * 128 + col] = v;
                            else
                                ((unsigned short*)Hout)[(size_t)row * 128 + col] = f2bf(v);
                        }
                    }
                }
            }
        }
    }
}

// ---------------- pull aggregation (bf16 gather): io[i] (+)= inv*sum t[nbr], opt relu ----
template <bool RELU, bool IOF32>
__global__ void k_agg(const unsigned short* __restrict__ t_mat,
                      const int* __restrict__ sorted_src,
                      const int* __restrict__ row_start, const int* __restrict__ deg,
                      const float* __restrict__ inv_deg, void* __restrict__ io) {
    int w = (blockIdx.x * blockDim.x + threadIdx.x) >> 6;
    int lane = threadIdx.x & 63;
    if (w >= N_NODES) return;
    int rs = row_start[w];
    int d = deg[w];
    float ax = 0.f, ay = 0.f;
    for (int q0 = 0; q0 < d; q0 += 64) {
        int nb = 0;
        if (q0 + lane < d) nb = sorted_src[rs + q0 + lane];
        int m = min(64, d - q0);
        for (int q = 0; q < m; ++q) {
            int j = __shfl(nb, q);
            unsigned int v = *(const unsigned int*)&t_mat[(size_t)j * 128 + lane * 2];
            ax += bf2f(v & 0xffffu);
            ay += __uint_as_float(v & 0xffff0000u);
        }
    }
    float inv = inv_deg[w];
    if (IOF32) {
        float* o = (float*)io + (size_t)w * 128 + lane * 2;
        float2 cur = *(float2*)o;
        float rx = cur.x + inv * ax;
        float ry = cur.y + inv * ay;
        if (RELU) { rx = fmaxf(rx, 0.f); ry = fmaxf(ry, 0.f); }
        float2 res; res.x = rx; res.y = ry;
        *(float2*)o = res;
    } else {
        unsigned short* o = (unsigned short*)io + (size_t)w * 128 + lane * 2;
        unsigned int cur = *(unsigned int*)o;
        float rx = bf2f(cur & 0xffffu) + inv * ax;
        float ry = __uint_as_float(cur & 0xffff0000u) + inv * ay;
        if (RELU) { rx = fmaxf(rx, 0.f); ry = fmaxf(ry, 0.f); }
        *(unsigned int*)o = (unsigned int)f2bf(rx) | ((unsigned int)f2bf(ry) << 16);
    }
}

// ---------------- launch ----------------

extern "C" void kernel_launch(void* const* d_in, const int* in_sizes, int n_in,
                              void* d_out, int out_size, void* d_ws, size_t ws_size,
                              hipStream_t stream) {
    const float* x   = (const float*)d_in[0];
    const int*   ei  = (const int*)d_in[1];
    const float* W1l = (const float*)d_in[2];
    const float* W1r = (const float*)d_in[3];
    const float* b1  = (const float*)d_in[4];
    const float* W2l = (const float*)d_in[5];
    const float* W2r = (const float*)d_in[6];
    const float* b2  = (const float*)d_in[7];
    float* out = (float*)d_out;

    const int* src = ei;
    const int* dst = ei + N_EDGES;

    char* p = (char*)d_ws;
    auto alloc = [&](size_t bytes) {
        char* r = p;
        p += (bytes + 255) & ~(size_t)255;
        return r;
    };
    unsigned short* xb    = (unsigned short*)alloc((size_t)N_NODES * D * 2); // 25.6MB
    unsigned short* tb    = (unsigned short*)alloc((size_t)N_NODES * D * 2); // 25.6MB
    unsigned short* hx    = (unsigned short*)alloc((size_t)N_NODES * D * 2); // 25.6MB
    int*   deg     = (int*)  alloc((size_t)N_NODES * sizeof(int));
    int*   rstart  = (int*)  alloc((size_t)N_NODES * sizeof(int));
    int*   cursor  = (int*)  alloc((size_t)N_NODES * sizeof(int));
    float* inv_deg = (float*)alloc((size_t)N_NODES * sizeof(float));
    int*   ssrc    = (int*)  alloc((size_t)N_EDGES * sizeof(int));
    int*   bsum    = (int*)  alloc(128 * sizeof(int));
    unsigned short* wc1 = (unsigned short*)alloc(256 * 128 * 2);
    unsigned short* wc2 = (unsigned short*)alloc(256 * 128 * 2);

    const int nb1024 = (N_NODES + 1023) / 1024;

    // CSR build
    k_zero_deg<<<(N_NODES + 255) / 256, 256, 0, stream>>>(deg);
    k_count_deg<<<(N_EDGES + 255) / 256, 256, 0, stream>>>(dst, deg);
    k_scan1<<<nb1024, 1024, 0, stream>>>(deg, rstart, bsum);
    k_scan2<<<1, 128, 0, stream>>>(bsum, nb1024);
    k_scan3<<<(N_NODES + 255) / 256, 256, 0, stream>>>(deg, rstart, bsum, cursor, inv_deg);
    k_sort<<<(N_EDGES + 255) / 256, 256, 0, stream>>>(src, dst, cursor, ssrc);

    // casts + weight packing
    k_cast_bf16<<<(N_NODES * D / 4 + 255) / 256, 256, 0, stream>>>(x, xb);
    k_pack_w<<<128, 256, 0, stream>>>(W1l, W1r, wc1);
    k_pack_w<<<128, 256, 0, stream>>>(W2l, W2r, wc2);

    const int agg_grid = (N_NODES + 3) / 4;

    // layer 1: [t|h_pre] = xb @ [W1l;W1r]^T (+b1 on h); h = relu(h_pre + mean t[nbrs])
    k_gemm_mfma<false><<<640, 256, 0, stream>>>(xb, wc1, b1, tb, hx);
    k_agg<true, false><<<agg_grid, 256, 0, stream>>>(tb, ssrc, rstart, deg, inv_deg, hx);

    // layer 2: [t|o_pre] = hx @ [W2l;W2r]^T (+b2 on o); out = o_pre + mean t[nbrs]
    k_gemm_mfma<true><<<640, 256, 0, stream>>>(hx, wc2, b2, tb, out);
    k_agg<false, true><<<agg_grid, 256, 0, stream>>>(tb, ssrc, rstart, deg, inv_deg, out);
}